// Round 10
// baseline (564.071 us; speedup 1.0000x reference)
//
#include <hip/hip_runtime.h>

#define B_ 256
#define T_ 512
#define I_ 256
#define H_ 256
#define CHUNK 64

typedef float    f32x4 __attribute__((ext_vector_type(4)));
typedef _Float16 f16x2 __attribute__((ext_vector_type(2)));
typedef _Float16 f16x8 __attribute__((ext_vector_type(8)));

static __device__ __forceinline__ f16x8 cvt8(f32x4 a, f32x4 b) {
  return f16x8{(_Float16)a[0], (_Float16)a[1], (_Float16)a[2], (_Float16)a[3],
               (_Float16)b[0], (_Float16)b[1], (_Float16)b[2], (_Float16)b[3]};
}

// ---------------- V0: fused RNN (verbatim round-8 369us kernel) ----------------
__global__ __launch_bounds__(512) void rnn_fused(const float* __restrict__ x,
                                                 const float* __restrict__ wxf,
                                                 const float* __restrict__ whf,
                                                 const float* __restrict__ bias_g,
                                                 float* __restrict__ io) {
  __shared__ __align__(16) float    xps[CHUNK][H_];
  __shared__ __align__(16) float    outs[CHUNK][H_];
  __shared__ __align__(16) _Float16 hb[2][H_];

  const int tid = threadIdx.x;
  const int l   = tid & 63;
  const int w   = tid >> 6;
  const int lr  = l & 15;
  const int g   = l >> 4;
  const int h0  = w * 32;
  const size_t base = (size_t)blockIdx.x * (size_t)(T_ * H_);

  f16x8 wB[16];
  f16x8 xB[16];
#pragma unroll
  for (int tile = 0; tile < 2; ++tile) {
#pragma unroll
    for (int kc = 0; kc < 8; ++kc) {
      const float* ph = whf + (size_t)(h0 + tile * 16 + lr) * H_ + kc * 32 + g * 8;
      wB[tile * 8 + kc] = cvt8(*(const f32x4*)ph, *(const f32x4*)(ph + 4));
      const float* px = wxf + (size_t)(h0 + tile * 16 + lr) * I_ + kc * 32 + g * 8;
      xB[tile * 8 + kc] = cvt8(*(const f32x4*)px, *(const f32x4*)(px + 4));
    }
  }
  const float bias0 = bias_g[h0 + lr];
  const float bias1 = bias_g[h0 + 16 + lr];
  if (tid < 128) ((f16x2*)hb[0])[tid] = f16x2{(_Float16)0.f, (_Float16)0.f};

  int cur = 0;
  for (int t0 = 0; t0 < T_; t0 += CHUNK) {
#pragma unroll 1
    for (int tt = 0; tt < CHUNK / 16; ++tt) {
      f32x4 aE0 = {}, aO0 = {}, aE1 = {}, aO1 = {};
      const float* xrow = x + base + (size_t)(t0 + tt * 16 + lr) * I_;
#pragma unroll
      for (int kc = 0; kc < 8; kc += 2) {
        const f32x4* p0 = (const f32x4*)(xrow + kc * 32 + g * 8);
        f16x8 a0 = cvt8(p0[0], p0[1]);
        const f32x4* p1 = (const f32x4*)(xrow + (kc + 1) * 32 + g * 8);
        f16x8 a1 = cvt8(p1[0], p1[1]);
        aE0 = __builtin_amdgcn_mfma_f32_16x16x32_f16(a0, xB[kc],         aE0, 0, 0, 0);
        aE1 = __builtin_amdgcn_mfma_f32_16x16x32_f16(a0, xB[8 + kc],     aE1, 0, 0, 0);
        aO0 = __builtin_amdgcn_mfma_f32_16x16x32_f16(a1, xB[kc + 1],     aO0, 0, 0, 0);
        aO1 = __builtin_amdgcn_mfma_f32_16x16x32_f16(a1, xB[8 + kc + 1], aO1, 0, 0, 0);
      }
      f32x4 y0 = aE0 + aO0, y1 = aE1 + aO1;
#pragma unroll
      for (int r = 0; r < 4; ++r) {
        xps[tt * 16 + g * 4 + r][h0 + lr]      = y0[r] + bias0;
        xps[tt * 16 + g * 4 + r][h0 + 16 + lr] = y1[r] + bias1;
      }
    }
    __syncthreads();

#pragma unroll 1
    for (int s = 0; s < CHUNK; ++s) {
      const float xp0 = xps[s][h0 + lr];
      const float xp1 = xps[s][h0 + 16 + lr];
      f32x4 aE0 = {}, aO0 = {}, aE1 = {}, aO1 = {};
      const f16x8* hp = (const f16x8*)hb[cur];
#pragma unroll
      for (int kc = 0; kc < 8; kc += 2) {
        f16x8 hv0 = hp[kc * 4 + g];
        f16x8 hv1 = hp[(kc + 1) * 4 + g];
        aE0 = __builtin_amdgcn_mfma_f32_16x16x32_f16(hv0, wB[kc],         aE0, 0, 0, 0);
        aE1 = __builtin_amdgcn_mfma_f32_16x16x32_f16(hv0, wB[8 + kc],     aE1, 0, 0, 0);
        aO0 = __builtin_amdgcn_mfma_f32_16x16x32_f16(hv1, wB[kc + 1],     aO0, 0, 0, 0);
        aO1 = __builtin_amdgcn_mfma_f32_16x16x32_f16(hv1, wB[8 + kc + 1], aO1, 0, 0, 0);
      }
      float y0 = aE0[0] + aO0[0] + xp0;
      float y1 = aE1[0] + aO1[0] + xp1;
      float e0 = __expf(2.f * y0);
      float hv0s = 1.f - 2.f * __builtin_amdgcn_rcpf(1.f + e0);
      float e1 = __expf(2.f * y1);
      float hv1s = 1.f - 2.f * __builtin_amdgcn_rcpf(1.f + e1);
      if (l < 16) {
        outs[s][h0 + lr]      = hv0s;
        outs[s][h0 + 16 + lr] = hv1s;
        _Float16* hn = hb[cur ^ 1];
        hn[h0 + lr]      = (_Float16)hv0s;
        hn[h0 + 16 + lr] = (_Float16)hv1s;
      }
      __syncthreads();
      cur ^= 1;
    }

    {
      const f32x4* src = (const f32x4*)outs;
      f32x4* dst = (f32x4*)(io + base + (size_t)t0 * H_);
#pragma unroll
      for (int i = 0; i < (CHUNK * H_ / 4) / 512; ++i)
        dst[i * 512 + tid] = src[i * 512 + tid];
    }
    __syncthreads();
  }
}

// ---------------- ABL 1: phase-2 only, h-frags from REGISTERS (no LDS h-read) ----------------
// 1024 steps (2x reps). Isolates the cost of the 8 broadcast ds_read_b128 per wave
// per step (+ their lgkm waits). Everything else identical to V0 phase 2.
// Output folded to ws (never touches d_out).
__global__ __launch_bounds__(512) void abl_noh(const float* __restrict__ whf,
                                               const float* __restrict__ bias_g,
                                               float* __restrict__ wsf) {
  __shared__ __align__(16) float    xps[CHUNK][H_];
  __shared__ __align__(16) float    outs[CHUNK][H_];
  __shared__ __align__(16) _Float16 hb[2][H_];

  const int tid = threadIdx.x;
  const int l   = tid & 63;
  const int w   = tid >> 6;
  const int lr  = l & 15;
  const int g   = l >> 4;
  const int h0  = w * 32;

  f16x8 wB[16];
#pragma unroll
  for (int tile = 0; tile < 2; ++tile) {
#pragma unroll
    for (int kc = 0; kc < 8; ++kc) {
      const float* ph = whf + (size_t)(h0 + tile * 16 + lr) * H_ + kc * 32 + g * 8;
      wB[tile * 8 + kc] = cvt8(*(const f32x4*)ph, *(const f32x4*)(ph + 4));
    }
  }
  const float bias0 = bias_g[h0 + lr];
  const float bias1 = bias_g[h0 + 16 + lr];
  if (tid < 128) ((f16x2*)hb[0])[tid] = f16x2{(_Float16)0.f, (_Float16)0.f};
  __syncthreads();

  // register h-fragments, loaded ONCE (replaces per-step LDS reads)
  f16x8 hc[8];
  const f16x8* hp0 = (const f16x8*)hb[0];
#pragma unroll
  for (int kc = 0; kc < 8; ++kc) hc[kc] = hp0[kc * 4 + g];

  int cur = 0;
#pragma unroll 1
  for (int c = 0; c < 16; ++c) {                      // 16 chunks = 2x reps of T
#pragma unroll 1
    for (int s = 0; s < CHUNK; ++s) {
      const float xp0 = xps[s][h0 + lr];              // junk values; cost identical
      const float xp1 = xps[s][h0 + 16 + lr];
      f32x4 aE0 = {}, aO0 = {}, aE1 = {}, aO1 = {};
#pragma unroll
      for (int kc = 0; kc < 8; kc += 2) {
        aE0 = __builtin_amdgcn_mfma_f32_16x16x32_f16(hc[kc],     wB[kc],         aE0, 0, 0, 0);
        aE1 = __builtin_amdgcn_mfma_f32_16x16x32_f16(hc[kc],     wB[8 + kc],     aE1, 0, 0, 0);
        aO0 = __builtin_amdgcn_mfma_f32_16x16x32_f16(hc[kc + 1], wB[kc + 1],     aO0, 0, 0, 0);
        aO1 = __builtin_amdgcn_mfma_f32_16x16x32_f16(hc[kc + 1], wB[8 + kc + 1], aO1, 0, 0, 0);
      }
      float y0 = aE0[0] + aO0[0] + xp0;
      float y1 = aE1[0] + aO1[0] + xp1;
      float e0 = __expf(2.f * y0);
      float hv0s = 1.f - 2.f * __builtin_amdgcn_rcpf(1.f + e0);
      float e1 = __expf(2.f * y1);
      float hv1s = 1.f - 2.f * __builtin_amdgcn_rcpf(1.f + e1);
      if (l < 16) {
        outs[s][h0 + lr]      = hv0s;
        outs[s][h0 + 16 + lr] = hv1s;
        _Float16* hn = hb[cur ^ 1];
        hn[h0 + lr]      = (_Float16)hv0s;
        hn[h0 + 16 + lr] = (_Float16)hv1s;
      }
      __syncthreads();
      cur ^= 1;
    }
  }
  // observe outs/hb so their stores can't be DCE'd; write junk to workspace
  float fin = outs[0][tid & 255] + (float)hb[0][tid & 255];
  wsf[((blockIdx.x << 9) + tid) & 32767] = fin;
}

// ---------------- ABL 2: skeleton — loop + one LDS read + barrier only ----------------
// 4096 iterations (8x the 512 steps), identical LDS footprint (132KB -> 1 block/CU),
// 8 waves. Measures the pure per-step sync/scheduling floor.
__global__ __launch_bounds__(512) void abl_skel(float* __restrict__ wsf) {
  __shared__ float skl[33024];                        // 132096 B, same as V0
  const int tid = threadIdx.x;
#pragma unroll 1
  for (int i = 0; i < 4096; ++i) {
    float r = skl[(i * 37 + (tid >> 4)) & 32767];     // varying addr, no dep chain
    asm volatile("" :: "v"(r));                       // keep read, no accumulation
    __syncthreads();
  }
  wsf[((blockIdx.x << 9) + tid) & 32767] = skl[tid];
}

extern "C" void kernel_launch(void* const* d_in, const int* in_sizes, int n_in,
                              void* d_out, int out_size, void* d_ws, size_t ws_size,
                              hipStream_t stream) {
  const float* x  = (const float*)d_in[0];
  const float* wx = (const float*)d_in[1];
  const float* wh = (const float*)d_in[2];
  const float* b  = (const float*)d_in[3];
  float* out = (float*)d_out;

  rnn_fused<<<B_, 512, 0, stream>>>(x, wx, wh, b, out);

  // ablation probes (info-round): write only to workspace, never to d_out
  if (ws_size >= 131072) {
    float* wsf = (float*)d_ws;
    abl_noh<<<B_, 512, 0, stream>>>(wh, b, wsf);
    abl_skel<<<B_, 512, 0, stream>>>(wsf);
  }
}